// Round 1
// baseline (1525.984 us; speedup 1.0000x reference)
//
#include <hip/hip_runtime.h>
#include <hip/hip_bf16.h>
#include <math.h>

// Problem constants (from reference setup_inputs): N=16384 nodes, F=64 feats, U=64 out
#define NN 16384
#define FF 64

typedef __bf16  bf16x8  __attribute__((ext_vector_type(8)));
typedef float   floatx4 __attribute__((ext_vector_type(4)));
typedef float   floatx8 __attribute__((ext_vector_type(8)));

// ---------------------------------------------------------------------------
// K1: x_projT[c][r] = bf16( expmap_scale(row r) * x[r][c] ), transposed layout
// expmap: n = min(||x_r||, 10); scale = tanh(n) / (n + 1e-8)
// ---------------------------------------------------------------------------
__global__ __launch_bounds__(256) void k_expmap_t(const float* __restrict__ x,
                                                  __bf16* __restrict__ xT) {
    __shared__ float xs[64][65];
    __shared__ float scl[64];
    const int tid = threadIdx.x;
    const int rb = blockIdx.x * 64;
    // load 64x64 tile, coalesced
    for (int i = 0; i < 16; ++i) {
        int idx = tid + i * 256;
        int r = idx >> 6, c = idx & 63;
        xs[r][c] = x[(size_t)(rb + r) * FF + c];
    }
    __syncthreads();
    if (tid < 64) {
        float ss = 0.f;
        for (int c = 0; c < 64; ++c) { float v = xs[tid][c]; ss += v * v; }
        float n = sqrtf(ss);
        n = fminf(n, 10.0f);
        scl[tid] = tanhf(n) / (n + 1e-8f);
    }
    __syncthreads();
    // write transposed, coalesced along original row index
    for (int i = 0; i < 16; ++i) {
        int idx = tid + i * 256;
        int c = idx >> 6, r = idx & 63;
        xT[(size_t)c * NN + rb + r] = (__bf16)(xs[r][c] * scl[r]);
    }
}

// ---------------------------------------------------------------------------
// K2: partial[kq] = adj[:, kq-slice] @ x_proj[kq-slice, :]   (MFMA, LDS-free)
// Each wave: 16 rows x 64 cols, K-range of len klen. A from adj fp32->bf16 on
// the fly (32B/lane contiguous); B from xT (16B/lane contiguous, cache-hot).
// grid = 256 * ksplit blocks of 256 threads (4 waves).
// ---------------------------------------------------------------------------
__global__ __launch_bounds__(256, 4) void k_gemm1(const float* __restrict__ adj,
                                                  const __bf16* __restrict__ xT,
                                                  float* __restrict__ pbuf,
                                                  int klen) {
    const int warp = threadIdx.x >> 6;
    const int lane = threadIdx.x & 63;
    const int group = blockIdx.x & 255;   // 64-row group
    const int kq    = blockIdx.x >> 8;    // k-slice id
    const int mtile = group * 4 + warp;   // 16-row tile
    const int quad  = lane >> 4;
    const int l15   = lane & 15;
    const int row   = mtile * 16 + l15;

    const long kbeg = (long)kq * klen;
    const long kend = kbeg + klen;

    floatx4 acc0 = {0.f, 0.f, 0.f, 0.f};
    floatx4 acc1 = {0.f, 0.f, 0.f, 0.f};
    floatx4 acc2 = {0.f, 0.f, 0.f, 0.f};
    floatx4 acc3 = {0.f, 0.f, 0.f, 0.f};

    const float*  arow = adj + (size_t)row * NN;
    const __bf16* b0p  = xT + (size_t)(l15 +  0) * NN;
    const __bf16* b1p  = xT + (size_t)(l15 + 16) * NN;
    const __bf16* b2p  = xT + (size_t)(l15 + 32) * NN;
    const __bf16* b3p  = xT + (size_t)(l15 + 48) * NN;

    #pragma unroll 2
    for (long k0 = kbeg; k0 < kend; k0 += 32) {
        const long ka = k0 + quad * 8;
        floatx8 af = *(const floatx8*)(arow + ka);
        bf16x8 a;
        #pragma unroll
        for (int j = 0; j < 8; ++j) a[j] = (__bf16)af[j];
        bf16x8 b0 = *(const bf16x8*)(b0p + ka);
        bf16x8 b1 = *(const bf16x8*)(b1p + ka);
        bf16x8 b2 = *(const bf16x8*)(b2p + ka);
        bf16x8 b3 = *(const bf16x8*)(b3p + ka);
        acc0 = __builtin_amdgcn_mfma_f32_16x16x32_bf16(a, b0, acc0, 0, 0, 0);
        acc1 = __builtin_amdgcn_mfma_f32_16x16x32_bf16(a, b1, acc1, 0, 0, 0);
        acc2 = __builtin_amdgcn_mfma_f32_16x16x32_bf16(a, b2, acc2, 0, 0, 0);
        acc3 = __builtin_amdgcn_mfma_f32_16x16x32_bf16(a, b3, acc3, 0, 0, 0);
    }

    // C/D layout (16x16x32): col = lane&15, row = (lane>>4)*4 + reg
    float* pb = pbuf + (size_t)kq * NN * FF;
    const int prow = mtile * 16 + quad * 4;
    #pragma unroll
    for (int reg = 0; reg < 4; ++reg) {
        float* dst = pb + (size_t)(prow + reg) * FF + l15;
        dst[0]  = acc0[reg];
        dst[16] = acc1[reg];
        dst[32] = acc2[reg];
        dst[48] = acc3[reg];
    }
}

// ---------------------------------------------------------------------------
// K3: support = sum(partials); out = logmap(support) @ kernel + bias
// logmap scale per row: nc = min(||s||, 0.999); atanh(nc)/(nc+1e-8)
// 32 rows per block of 256 threads.
// ---------------------------------------------------------------------------
__global__ __launch_bounds__(256) void k_finish(const float* __restrict__ pbuf,
                                                const float* __restrict__ kern,
                                                const float* __restrict__ bias,
                                                float* __restrict__ out,
                                                int ksplit) {
    __shared__ float S[32][65];
    __shared__ float KL[64][68];
    __shared__ float scl[32];
    const int tid = threadIdx.x;
    const int rb = blockIdx.x * 32;

    // stage kernel matrix (64x64 fp32)
    for (int i = tid; i < 4096; i += 256) KL[i >> 6][i & 63] = kern[i];
    // combine K-split partials
    for (int i = tid; i < 2048; i += 256) {
        int r = i >> 6, c = i & 63;
        size_t off = (size_t)(rb + r) * FF + c;
        float s = 0.f;
        for (int q = 0; q < ksplit; ++q) s += pbuf[(size_t)q * NN * FF + off];
        S[r][c] = s;
    }
    __syncthreads();
    if (tid < 32) {
        float ss = 0.f;
        for (int c = 0; c < 64; ++c) { float v = S[tid][c]; ss += v * v; }
        float n = sqrtf(ss);
        float nc = fminf(n, 0.999f);
        scl[tid] = atanhf(nc) / (nc + 1e-8f);
    }
    __syncthreads();
    // second gemm: each thread computes 8 outputs of one row
    const int r  = tid >> 3;
    const int u0 = (tid & 7) * 8;
    float acc[8];
    #pragma unroll
    for (int j = 0; j < 8; ++j) acc[j] = bias[u0 + j];
    const float sc = scl[r];
    for (int f = 0; f < 64; ++f) {
        float sv = S[r][f] * sc;
        #pragma unroll
        for (int j = 0; j < 8; ++j) acc[j] += sv * KL[f][u0 + j];
    }
    float* op = out + (size_t)(rb + r) * FF + u0;
    #pragma unroll
    for (int j = 0; j < 8; ++j) op[j] = acc[j];
}

// ---------------------------------------------------------------------------
extern "C" void kernel_launch(void* const* d_in, const int* in_sizes, int n_in,
                              void* d_out, int out_size, void* d_ws, size_t ws_size,
                              hipStream_t stream) {
    const float* x    = (const float*)d_in[0];   // [16384, 64]
    const float* adj  = (const float*)d_in[1];   // [16384, 16384]
    const float* kern = (const float*)d_in[2];   // [64, 64]
    const float* bias = (const float*)d_in[3];   // [64]
    float* out = (float*)d_out;                  // [16384, 64]

    char* ws = (char*)d_ws;
    const size_t xT_bytes = (size_t)FF * NN * sizeof(__bf16);      // 2 MiB
    __bf16* xT = (__bf16*)ws;
    const size_t pbuf_elems = (size_t)NN * FF;                     // 1M floats / slice

    // pick ksplit that fits workspace; fall back to using d_out as the single
    // partial buffer if ws is tiny (K3 reads/writes the same rows per block).
    int ksplit = 4;
    float* pbuf = (float*)(ws + xT_bytes);
    while (ksplit > 1 &&
           xT_bytes + (size_t)ksplit * pbuf_elems * sizeof(float) > ws_size)
        ksplit >>= 1;
    if (xT_bytes + (size_t)ksplit * pbuf_elems * sizeof(float) > ws_size) {
        ksplit = 1;
        pbuf = out;  // safe: K3 block reads exactly the rows it overwrites
    }

    // K1: expmap + transpose to bf16
    k_expmap_t<<<dim3(NN / 64), dim3(256), 0, stream>>>(x, xT);
    // K2: big GEMM, K split ksplit ways
    k_gemm1<<<dim3(256 * ksplit), dim3(256), 0, stream>>>(adj, xT, pbuf, NN / ksplit);
    // K3: combine + logmap + small GEMM + bias
    k_finish<<<dim3(NN / 32), dim3(256), 0, stream>>>(pbuf, kern, bias, out, ksplit);
}